// Round 10
// baseline (4723.246 us; speedup 1.0000x reference)
//
#include <hip/hip_runtime.h>
#include <hip/hip_bf16.h>

#define DEV __device__ __forceinline__

DEV float4 ld4(const float* p) { return *reinterpret_cast<const float4*>(p); }
DEV float sigmoidf_(float x) { return 1.f / (1.f + expf(-x)); }

DEV void fma8(float (&a)[8], float xv, float4 wa, float4 wb) {
  a[0] = fmaf(xv, wa.x, a[0]); a[1] = fmaf(xv, wa.y, a[1]);
  a[2] = fmaf(xv, wa.z, a[2]); a[3] = fmaf(xv, wa.w, a[3]);
  a[4] = fmaf(xv, wb.x, a[4]); a[5] = fmaf(xv, wb.y, a[5]);
  a[6] = fmaf(xv, wb.z, a[6]); a[7] = fmaf(xv, wb.w, a[7]);
}
DEV void fma4(float (&a)[4], float xv, float4 wa) {
  a[0] = fmaf(xv, wa.x, a[0]); a[1] = fmaf(xv, wa.y, a[1]);
  a[2] = fmaf(xv, wa.z, a[2]); a[3] = fmaf(xv, wa.w, a[3]);
}
DEV float4 wfma4(float4 a, float w, float4 r) {
  a.x = __fadd_rn(a.x, __fmul_rn(w, r.x));
  a.y = __fadd_rn(a.y, __fmul_rn(w, r.y));
  a.z = __fadd_rn(a.z, __fmul_rn(w, r.z));
  a.w = __fadd_rn(a.w, __fmul_rn(w, r.w));
  return a;
}

// ---------------- CSR build (deterministic, stable) ----------------

__global__ void count_kernel(const int* __restrict__ dst, int* __restrict__ cnt, int E) {
  int e = blockIdx.x * blockDim.x + threadIdx.x;
  if (e < E) atomicAdd(&cnt[dst[e]], 1);  // counts order-independent -> deterministic
}

__global__ __launch_bounds__(256) void blockreduce_kernel(const int* __restrict__ cnt,
                                                          int* __restrict__ bsum, int n) {
  int i = blockIdx.x * 256 + threadIdx.x;
  int v = (i < n) ? cnt[i] : 0;
#pragma unroll
  for (int d = 1; d < 64; d <<= 1) v += __shfl_xor(v, d, 64);
  __shared__ int sh[4];
  if ((threadIdx.x & 63) == 0) sh[threadIdx.x >> 6] = v;
  __syncthreads();
  if (threadIdx.x == 0) bsum[blockIdx.x] = sh[0] + sh[1] + sh[2] + sh[3];
}

__global__ __launch_bounds__(256) void scanb_kernel(const int* __restrict__ bsum,
                                                    int* __restrict__ boff, int nb) {
  __shared__ int sh[256];
  int t = threadIdx.x;
  int orig = (t < nb) ? bsum[t] : 0;
  int v = orig;
  sh[t] = v;
  __syncthreads();
  for (int d = 1; d < 256; d <<= 1) {
    int a = (t >= d) ? sh[t - d] : 0;
    __syncthreads();
    v += a;
    sh[t] = v;
    __syncthreads();
  }
  if (t < nb) boff[t] = v - orig;  // exclusive
}

__global__ __launch_bounds__(256) void blockscan_kernel(
    const int* __restrict__ cnt, const int* __restrict__ boff,
    int* __restrict__ off, int* __restrict__ cur, int n, int total) {
  __shared__ int sh[256];
  int b = blockIdx.x, t = threadIdx.x;
  int i = b * 256 + t;
  int orig = (i < n) ? cnt[i] : 0;
  int v = orig;
  sh[t] = v;
  __syncthreads();
  for (int d = 1; d < 256; d <<= 1) {
    int a = (t >= d) ? sh[t - d] : 0;
    __syncthreads();
    v += a;
    sh[t] = v;
    __syncthreads();
  }
  int excl = v - orig + boff[b];
  if (i < n) { off[i] = excl; cur[i] = excl; }
  if (i == n - 1) off[n] = total;
}

__global__ void scatter_kernel(const int* __restrict__ dstI, int* __restrict__ cur,
                               int* __restrict__ eidx, int E) {
  int e = blockIdx.x * blockDim.x + threadIdx.x;
  if (e < E) {
    int p = atomicAdd(&cur[dstI[e]], 1);
    eidx[p] = e;
  }
}

// per-node wave rank-sort by edge index -> deterministic stable order
// (ascending edge index == np.add.at accumulation order).
__global__ __launch_bounds__(256) void sortseg_kernel(
    const int* __restrict__ off, int* __restrict__ eidx,
    const int* __restrict__ srcI, const float* __restrict__ ew,
    int2* __restrict__ cse, int n) {
  int node = blockIdx.x * 4 + (threadIdx.x >> 6);
  int lane = threadIdx.x & 63;
  if (node >= n) return;
  int s = off[node], e = off[node + 1];
  int deg = e - s;
  if (deg <= 0) return;
  if (deg <= 64) {
    int v = (lane < deg) ? eidx[s + lane] : 2147483647;
    int rank = 0;
    for (int m = 0; m < 64; ++m) {
      int u = __shfl(v, m, 64);
      rank += (u < v) ? 1 : 0;  // edge indices unique
    }
    if (lane < deg)
      cse[s + rank] = make_int2(srcI[v], __float_as_int(ew[v]));
  } else if (lane == 0) {
    for (int i = s + 1; i < e; ++i) {
      int key = eidx[i]; int j = i - 1;
      while (j >= s && eidx[j] > key) { eidx[j + 1] = eidx[j]; --j; }
      eidx[j + 1] = key;
    }
    for (int i = s; i < e; ++i) {
      int v = eidx[i];
      cse[i] = make_int2(srcI[v], __float_as_int(ew[v]));
    }
  }
}

// ---------------- degree-bucketed node permutation ----------------
// Equalizes chain length across the 16-lane groups of a wave/block.
// The permutation need NOT be deterministic: each node's chain and output
// location are fixed, so d_out is bit-identical regardless of placement.

__global__ __launch_bounds__(256) void deghist_kernel(
    const int* __restrict__ off, int* __restrict__ ghist, int n, int nb) {
  __shared__ int h[256];
  int t = threadIdx.x, b = blockIdx.x;
  h[t] = 0;
  __syncthreads();
  int i = b * 256 + t;
  if (i < n) {
    int d = min(off[i + 1] - off[i], 255);
    atomicAdd(&h[d], 1);  // LDS atomic; counts deterministic
  }
  __syncthreads();
  ghist[t * nb + b] = h[t];  // bin-major layout for the global scan
}

__global__ __launch_bounds__(256) void degplace_kernel(
    const int* __restrict__ off, const int* __restrict__ goff,
    int* __restrict__ perm, int n, int nb) {
  __shared__ int cur[256];
  int t = threadIdx.x, b = blockIdx.x;
  cur[t] = goff[t * nb + b];
  __syncthreads();
  int i = b * 256 + t;
  if (i < n) {
    int d = min(off[i + 1] - off[i], 255);
    int pos = atomicAdd(&cur[d], 1);
    perm[pos] = i;
  }
}

// layer-0 x aggregation for all timesteps (graph is time-invariant)
__global__ __launch_bounds__(256) void aggx0_kernel(
    const int* __restrict__ off, const int2* __restrict__ cse,
    const float* __restrict__ x, float* __restrict__ ax, int n) {
  int node = blockIdx.x * 8 + (threadIdx.x >> 5);
  int lane = threadIdx.x & 31;
  if (node >= n || lane >= 24) return;
  float a = 0.f;
  int s = off[node], e = off[node + 1];
  int i = s;
  for (; i + 3 < e; i += 4) {
    int2 p0 = cse[i], p1 = cse[i + 1], p2 = cse[i + 2], p3 = cse[i + 3];
    float r0 = x[(size_t)p0.x * 24 + lane];
    float r1 = x[(size_t)p1.x * 24 + lane];
    float r2 = x[(size_t)p2.x * 24 + lane];
    float r3 = x[(size_t)p3.x * 24 + lane];
    a = __fadd_rn(a, __fmul_rn(__int_as_float(p0.y), r0));
    a = __fadd_rn(a, __fmul_rn(__int_as_float(p1.y), r1));
    a = __fadd_rn(a, __fmul_rn(__int_as_float(p2.y), r2));
    a = __fadd_rn(a, __fmul_rn(__int_as_float(p3.y), r3));
  }
  for (; i < e; ++i) {
    int2 p = cse[i];
    a = __fadd_rn(a, __fmul_rn(__int_as_float(p.y), x[(size_t)p.x * 24 + lane]));
  }
  ax[(size_t)node * 24 + lane] = a;
}

// ---------------- aggregation (pull, CSR, degree-balanced) ----------------
// 16-lane group per node, float4 per lane => one full 256B row per edge.
// cse double-buffer; strict ascending edge order -> bit-identical chains.

__global__ __launch_bounds__(256) void agg1_kernel(
    const int* __restrict__ off, const int2* __restrict__ cse,
    const int* __restrict__ perm,
    const float* __restrict__ f0, float* __restrict__ o0, int n) {
  const int gi = blockIdx.x * 16 + (threadIdx.x >> 4);
  const int g4 = (threadIdx.x & 15) * 4;
  if (gi >= n) return;
  const int node = perm[gi];
  int s = off[node], e = off[node + 1];
  float4 acc = make_float4(0.f, 0.f, 0.f, 0.f);
  int i = s;
  if (i + 3 < e) {
    int2 q0 = cse[i], q1 = cse[i + 1], q2 = cse[i + 2], q3 = cse[i + 3];
    for (; i + 7 < e; i += 4) {
      float4 r0 = ld4(f0 + (size_t)q0.x * 64 + g4);
      float4 r1 = ld4(f0 + (size_t)q1.x * 64 + g4);
      float4 r2 = ld4(f0 + (size_t)q2.x * 64 + g4);
      float4 r3 = ld4(f0 + (size_t)q3.x * 64 + g4);
      int2 m0 = cse[i + 4], m1 = cse[i + 5], m2 = cse[i + 6], m3 = cse[i + 7];
      acc = wfma4(acc, __int_as_float(q0.y), r0);
      acc = wfma4(acc, __int_as_float(q1.y), r1);
      acc = wfma4(acc, __int_as_float(q2.y), r2);
      acc = wfma4(acc, __int_as_float(q3.y), r3);
      q0 = m0; q1 = m1; q2 = m2; q3 = m3;
    }
    float4 r0 = ld4(f0 + (size_t)q0.x * 64 + g4);
    float4 r1 = ld4(f0 + (size_t)q1.x * 64 + g4);
    float4 r2 = ld4(f0 + (size_t)q2.x * 64 + g4);
    float4 r3 = ld4(f0 + (size_t)q3.x * 64 + g4);
    acc = wfma4(acc, __int_as_float(q0.y), r0);
    acc = wfma4(acc, __int_as_float(q1.y), r1);
    acc = wfma4(acc, __int_as_float(q2.y), r2);
    acc = wfma4(acc, __int_as_float(q3.y), r3);
    i += 4;
  }
  for (; i < e; ++i) {
    int2 p = cse[i];
    acc = wfma4(acc, __int_as_float(p.y), ld4(f0 + (size_t)p.x * 64 + g4));
  }
  *reinterpret_cast<float4*>(o0 + (size_t)node * 64 + g4) = acc;
}

// fused double gather (two tables, shared index stream), 4-edge unroll + cse dbuf
__global__ __launch_bounds__(256) void agg2_kernel(
    const int* __restrict__ off, const int2* __restrict__ cse,
    const int* __restrict__ perm,
    const float* __restrict__ f0, float* __restrict__ o0,
    const float* __restrict__ f1, float* __restrict__ o1, int n) {
  const int gi = blockIdx.x * 16 + (threadIdx.x >> 4);
  const int g4 = (threadIdx.x & 15) * 4;
  if (gi >= n) return;
  const int node = perm[gi];
  int s = off[node], e = off[node + 1];
  float4 a0 = make_float4(0.f, 0.f, 0.f, 0.f);
  float4 a1 = a0;
  int i = s;
  if (i + 3 < e) {
    int2 q0 = cse[i], q1 = cse[i + 1], q2 = cse[i + 2], q3 = cse[i + 3];
    for (; i + 7 < e; i += 4) {
      size_t o0_ = (size_t)q0.x * 64 + g4, o1_ = (size_t)q1.x * 64 + g4;
      size_t o2_ = (size_t)q2.x * 64 + g4, o3_ = (size_t)q3.x * 64 + g4;
      float4 x0 = ld4(f0 + o0_), h0 = ld4(f1 + o0_);
      float4 x1 = ld4(f0 + o1_), h1 = ld4(f1 + o1_);
      float4 x2 = ld4(f0 + o2_), h2 = ld4(f1 + o2_);
      float4 x3 = ld4(f0 + o3_), h3 = ld4(f1 + o3_);
      int2 m0 = cse[i + 4], m1 = cse[i + 5], m2 = cse[i + 6], m3 = cse[i + 7];
      float w0 = __int_as_float(q0.y), w1 = __int_as_float(q1.y);
      float w2 = __int_as_float(q2.y), w3 = __int_as_float(q3.y);
      a0 = wfma4(a0, w0, x0); a1 = wfma4(a1, w0, h0);
      a0 = wfma4(a0, w1, x1); a1 = wfma4(a1, w1, h1);
      a0 = wfma4(a0, w2, x2); a1 = wfma4(a1, w2, h2);
      a0 = wfma4(a0, w3, x3); a1 = wfma4(a1, w3, h3);
      q0 = m0; q1 = m1; q2 = m2; q3 = m3;
    }
    size_t o0_ = (size_t)q0.x * 64 + g4, o1_ = (size_t)q1.x * 64 + g4;
    size_t o2_ = (size_t)q2.x * 64 + g4, o3_ = (size_t)q3.x * 64 + g4;
    float4 x0 = ld4(f0 + o0_), h0 = ld4(f1 + o0_);
    float4 x1 = ld4(f0 + o1_), h1 = ld4(f1 + o1_);
    float4 x2 = ld4(f0 + o2_), h2 = ld4(f1 + o2_);
    float4 x3 = ld4(f0 + o3_), h3 = ld4(f1 + o3_);
    float w0 = __int_as_float(q0.y), w1 = __int_as_float(q1.y);
    float w2 = __int_as_float(q2.y), w3 = __int_as_float(q3.y);
    a0 = wfma4(a0, w0, x0); a1 = wfma4(a1, w0, h0);
    a0 = wfma4(a0, w1, x1); a1 = wfma4(a1, w1, h1);
    a0 = wfma4(a0, w2, x2); a1 = wfma4(a1, w2, h2);
    a0 = wfma4(a0, w3, x3); a1 = wfma4(a1, w3, h3);
    i += 4;
  }
  for (; i < e; ++i) {
    int2 p = cse[i];
    float w = __int_as_float(p.y);
    size_t ro = (size_t)p.x * 64 + g4;
    a0 = wfma4(a0, w, ld4(f0 + ro));
    a1 = wfma4(a1, w, ld4(f1 + ro));
  }
  *reinterpret_cast<float4*>(o0 + (size_t)node * 64 + g4) = a0;
  *reinterpret_cast<float4*>(o1 + (size_t)node * 64 + g4) = a1;
}

// ---------------- gates: zr = sigmoid([aggx, aggh] @ Wg + bg) ----------------
// LDS-staged weights; 8 rows/thread x 8 outs, 128 rows/block.

template <int KX>
__global__ __launch_bounds__(256) void gates_kernel(
    const float* __restrict__ aggx, int sx,
    const float* __restrict__ aggh,
    const float* __restrict__ Wg, const float* __restrict__ bg,
    const float* __restrict__ hb, float* __restrict__ zb, float* __restrict__ rhb, int n) {
  __shared__ float wS[(KX + 64) * 128];
  const int t = threadIdx.x;
  {
    float4* d = (float4*)wS;
    const float4* src = (const float4*)Wg;
    const int tot = (KX + 64) * 32;
    for (int idx = t; idx < tot; idx += 256) d[idx] = src[idx];
  }
  __syncthreads();

  const int j0 = (t & 15) * 8;
  const int rb = blockIdx.x * 128 + (t >> 4) * 8;
  if (rb >= n) return;
  const int nr = min(8, n - rb);
  int ro[8];
#pragma unroll
  for (int r = 0; r < 8; ++r) ro[r] = (rb + (r < nr ? r : 0)) * 64;

  float a[8][8];
#pragma unroll
  for (int r = 0; r < 8; ++r)
#pragma unroll
    for (int i = 0; i < 8; ++i) a[r][i] = 0.f;

  {
    const float* Wh = wS + KX * 128;
    for (int k = 0; k < 64; k += 4) {
      float4 f[8];
#pragma unroll
      for (int r = 0; r < 8; ++r) f[r] = ld4(aggh + ro[r] + k);
#pragma unroll
      for (int kk = 0; kk < 4; ++kk) {
        const float* wr = Wh + (k + kk) * 128 + j0;
        float4 wa = ld4(wr), wb = ld4(wr + 4);
#pragma unroll
        for (int r = 0; r < 8; ++r) fma8(a[r], ((const float*)&f[r])[kk], wa, wb);
      }
    }
  }
  if constexpr (KX == 2) {
    float xv[8][2];
#pragma unroll
    for (int r = 0; r < 8; ++r) {
      size_t xo = (size_t)(rb + (r < nr ? r : 0)) * sx;
      xv[r][0] = aggx[xo]; xv[r][1] = aggx[xo + 1];
    }
#pragma unroll
    for (int k = 0; k < 2; ++k) {
      const float* wr = wS + k * 128 + j0;
      float4 wa = ld4(wr), wb = ld4(wr + 4);
#pragma unroll
      for (int r = 0; r < 8; ++r) fma8(a[r], xv[r][k], wa, wb);
    }
  } else {
    for (int k = 0; k < KX; k += 4) {
      float4 f[8];
#pragma unroll
      for (int r = 0; r < 8; ++r) f[r] = ld4(aggx + ro[r] + k);
#pragma unroll
      for (int kk = 0; kk < 4; ++kk) {
        const float* wr = wS + (k + kk) * 128 + j0;
        float4 wa = ld4(wr), wb = ld4(wr + 4);
#pragma unroll
        for (int r = 0; r < 8; ++r) fma8(a[r], ((const float*)&f[r])[kk], wa, wb);
      }
    }
  }
#pragma unroll
  for (int i = 0; i < 8; ++i) {
    int j = j0 + i;
    float b = bg[j];
#pragma unroll
    for (int r = 0; r < 8; ++r) {
      if (r < nr) {
        int row = rb + r;
        float sg = sigmoidf_(a[r][i] + b);
        if (j < 64) {
          zb[(size_t)row * 64 + j] = sg;
        } else {
          int jj = j - 64;
          rhb[(size_t)row * 64 + jj] = __fmul_rn(sg, hb[(size_t)row * 64 + jj]);
        }
      }
    }
  }
}

// ---------------- candidate + GRU update ----------------
// LDS-staged weights, 8 rows/thread x 4 outs, 128 rows/block.

template <int KX>
__global__ __launch_bounds__(256) void cand_kernel(
    const float* __restrict__ aggx, int sx,
    const float* __restrict__ aggrh,
    const float* __restrict__ Wc, const float* __restrict__ bc,
    const float* __restrict__ zb, float* __restrict__ hb,
    float* __restrict__ outp, int ostride, int n) {
  __shared__ float wS[(KX + 64) * 64];
  const int t = threadIdx.x;
  {
    float4* d = (float4*)wS;
    const float4* src = (const float4*)Wc;
    const int tot = (KX + 64) * 16;
    for (int idx = t; idx < tot; idx += 256) d[idx] = src[idx];
  }
  __syncthreads();

  const int j0 = (t & 15) * 4;
  const int rb = blockIdx.x * 128 + (t >> 4) * 8;
  if (rb >= n) return;
  const int nr = min(8, n - rb);
  int ro[8];
#pragma unroll
  for (int r = 0; r < 8; ++r) ro[r] = (rb + (r < nr ? r : 0)) * 64;

  float a[8][4];
#pragma unroll
  for (int r = 0; r < 8; ++r)
#pragma unroll
    for (int i = 0; i < 4; ++i) a[r][i] = 0.f;

  {
    const float* Wh = wS + KX * 64;
    for (int k = 0; k < 64; k += 4) {
      float4 f[8];
#pragma unroll
      for (int r = 0; r < 8; ++r) f[r] = ld4(aggrh + ro[r] + k);
#pragma unroll
      for (int kk = 0; kk < 4; ++kk) {
        float4 wa = ld4(Wh + (k + kk) * 64 + j0);
#pragma unroll
        for (int r = 0; r < 8; ++r) fma4(a[r], ((const float*)&f[r])[kk], wa);
      }
    }
  }
  if constexpr (KX == 2) {
    float xv[8][2];
#pragma unroll
    for (int r = 0; r < 8; ++r) {
      size_t xo = (size_t)(rb + (r < nr ? r : 0)) * sx;
      xv[r][0] = aggx[xo]; xv[r][1] = aggx[xo + 1];
    }
#pragma unroll
    for (int k = 0; k < 2; ++k) {
      float4 wa = ld4(wS + k * 64 + j0);
#pragma unroll
      for (int r = 0; r < 8; ++r) fma4(a[r], xv[r][k], wa);
    }
  } else {
    for (int k = 0; k < KX; k += 4) {
      float4 f[8];
#pragma unroll
      for (int r = 0; r < 8; ++r) f[r] = ld4(aggx + ro[r] + k);
#pragma unroll
      for (int kk = 0; kk < 4; ++kk) {
        float4 wa = ld4(wS + (k + kk) * 64 + j0);
#pragma unroll
        for (int r = 0; r < 8; ++r) fma4(a[r], ((const float*)&f[r])[kk], wa);
      }
    }
  }
#pragma unroll
  for (int i = 0; i < 4; ++i) {
    int j = j0 + i;
    float b = bc[j];
#pragma unroll
    for (int r = 0; r < 8; ++r) {
      if (r < nr) {
        int row = rb + r;
        float c = tanhf(a[r][i] + b);
        float z = zb[(size_t)row * 64 + j];
        float h = hb[(size_t)row * 64 + j];
        float hn = __fadd_rn(__fmul_rn(z, h), __fmul_rn(1.f - z, c));  // np rounding
        hb[(size_t)row * 64 + j] = hn;
        outp[(size_t)row * ostride + j] = hn;
      }
    }
  }
}

// ---------------- launch ----------------

extern "C" void kernel_launch(void* const* d_in, const int* in_sizes, int n_in,
                              void* d_out, int out_size, void* d_ws, size_t ws_size,
                              hipStream_t stream) {
  const float* x   = (const float*)d_in[0];
  const float* h0  = (const float*)d_in[1];
  const int*   ei  = (const int*)  d_in[2];
  const float* ew  = (const float*)d_in[3];
  const float* Wg0 = (const float*)d_in[4];
  const float* bg0 = (const float*)d_in[5];
  const float* Wc0 = (const float*)d_in[6];
  const float* bc0 = (const float*)d_in[7];
  const float* Wg1 = (const float*)d_in[8];
  const float* bg1 = (const float*)d_in[9];
  const float* Wc1 = (const float*)d_in[10];
  const float* bc1 = (const float*)d_in[11];

  const int N = in_sizes[0] / 24;  // T*F = 24
  const int E = in_sizes[2] / 2;
  const int NH = N * 64;
  const int NB = (N + 255) / 256;       // node blocks (<=256)
  const int NG = 256 * NB;              // ghist size
  const int NB2 = (NG + 255) / 256;     // blocks for ghist scan (<=256)

  float* h1   = (float*)d_out;      // N*64
  float* h2   = h1 + NH;            // N*64
  float* out2 = h2 + NH;            // N*T*64, layout [n][t][j]

  char* w = (char*)d_ws;
  auto alloc = [&](size_t bytes) {
    char* p = w;
    w += (bytes + 255) & ~(size_t)255;
    return p;
  };
  int*   cnt   = (int*)  alloc((size_t)N * 4);
  int*   off   = (int*)  alloc((size_t)(N + 1) * 4);
  int*   cur   = (int*)  alloc((size_t)N * 4);
  int2*  cse   = (int2*) alloc((size_t)E * 8);   // packed (src, weight)
  int*   bsum  = (int*)  alloc(256 * 4);
  int*   boff  = (int*)  alloc(256 * 4);
  int*   perm  = (int*)  alloc((size_t)N * 4);
  int*   ghist = (int*)  alloc((size_t)NG * 4);
  int*   goff  = (int*)  alloc((size_t)(NG + 1) * 4);
  int*   gcur  = (int*)  alloc((size_t)NG * 4);
  float* aggx0 = (float*)alloc((size_t)N * 24 * 4);
  float* aggx1 = (float*)alloc((size_t)NH * 4);
  float* aggh  = (float*)alloc((size_t)NH * 4);
  float* aggrh = (float*)alloc((size_t)NH * 4);
  float* zb    = (float*)alloc((size_t)NH * 4);
  float* rhb   = (float*)alloc((size_t)NH * 4);
  float* o1t   = (float*)alloc((size_t)NH * 4);
  int*   eidx  = (int*)aggx1;  // alias: aggx1 first written inside the t-loop

  const int* srcI = ei;
  const int* dstI = ei + E;

  hipMemcpyAsync(d_out, h0, (size_t)2 * NH * 4, hipMemcpyDeviceToDevice, stream);

  // deterministic & stable CSR: sorted by (dst, original edge index)
  hipMemsetAsync(cnt, 0, (size_t)N * 4, stream);
  count_kernel<<<(E + 255) / 256, 256, 0, stream>>>(dstI, cnt, E);
  blockreduce_kernel<<<NB, 256, 0, stream>>>(cnt, bsum, N);
  scanb_kernel<<<1, 256, 0, stream>>>(bsum, boff, NB);
  blockscan_kernel<<<NB, 256, 0, stream>>>(cnt, boff, off, cur, N, E);
  scatter_kernel<<<(E + 255) / 256, 256, 0, stream>>>(dstI, cur, eidx, E);
  sortseg_kernel<<<(N + 3) / 4, 256, 0, stream>>>(off, eidx, srcI, ew, cse, N);

  // degree-bucketed permutation (output-invariant; no hot global atomics)
  deghist_kernel<<<NB, 256, 0, stream>>>(off, ghist, N, NB);
  blockreduce_kernel<<<NB2, 256, 0, stream>>>(ghist, bsum, NG);
  scanb_kernel<<<1, 256, 0, stream>>>(bsum, boff, NB2);
  blockscan_kernel<<<NB2, 256, 0, stream>>>(ghist, boff, goff, gcur, NG, N);
  degplace_kernel<<<NB, 256, 0, stream>>>(off, goff, perm, N, NB);

  // layer-0 x aggregation, all timesteps at once (graph is time-invariant)
  aggx0_kernel<<<(N + 7) / 8, 256, 0, stream>>>(off, cse, x, aggx0, N);

  const int gagg = (N + 15) / 16;   // 16 nodes/block (16-lane group per node)
  const int gmm  = (N + 127) / 128; // matmuls: 128 rows/block, 8 rows/thread

  for (int t = 0; t < 12; ++t) {
    // ---- layer 0 ----
    agg1_kernel<<<gagg, 256, 0, stream>>>(off, cse, perm, h1, aggh, N);
    gates_kernel<2><<<gmm, 256, 0, stream>>>(aggx0 + 2 * t, 24, aggh, Wg0, bg0, h1, zb, rhb, N);
    agg1_kernel<<<gagg, 256, 0, stream>>>(off, cse, perm, rhb, aggrh, N);
    cand_kernel<2><<<gmm, 256, 0, stream>>>(aggx0 + 2 * t, 24, aggrh, Wc0, bc0, zb, h1, o1t, 64, N);
    // ---- layer 1 ----
    agg2_kernel<<<gagg, 256, 0, stream>>>(off, cse, perm, o1t, aggx1, h2, aggh, N);
    gates_kernel<64><<<gmm, 256, 0, stream>>>(aggx1, 64, aggh, Wg1, bg1, h2, zb, rhb, N);
    agg1_kernel<<<gagg, 256, 0, stream>>>(off, cse, perm, rhb, aggrh, N);
    cand_kernel<64><<<gmm, 256, 0, stream>>>(aggx1, 64, aggrh, Wc1, bc1, zb, h2,
                                             out2 + (size_t)t * 64, 12 * 64, N);
  }
}

// Round 11
// 3904.869 us; speedup vs baseline: 1.2096x; 1.2096x over previous
//
#include <hip/hip_runtime.h>
#include <hip/hip_bf16.h>

#define DEV __device__ __forceinline__

DEV float4 ld4(const float* p) { return *reinterpret_cast<const float4*>(p); }
DEV float sigmoidf_(float x) { return 1.f / (1.f + expf(-x)); }

DEV void fma4(float (&a)[4], float xv, float4 wa) {
  a[0] = fmaf(xv, wa.x, a[0]); a[1] = fmaf(xv, wa.y, a[1]);
  a[2] = fmaf(xv, wa.z, a[2]); a[3] = fmaf(xv, wa.w, a[3]);
}
DEV float4 wfma4(float4 a, float w, float4 r) {
  a.x = __fadd_rn(a.x, __fmul_rn(w, r.x));
  a.y = __fadd_rn(a.y, __fmul_rn(w, r.y));
  a.z = __fadd_rn(a.z, __fmul_rn(w, r.z));
  a.w = __fadd_rn(a.w, __fmul_rn(w, r.w));
  return a;
}

// ---------------- CSR build (deterministic, stable) ----------------

__global__ void count_kernel(const int* __restrict__ dst, int* __restrict__ cnt, int E) {
  int e = blockIdx.x * blockDim.x + threadIdx.x;
  if (e < E) atomicAdd(&cnt[dst[e]], 1);  // counts order-independent -> deterministic
}

__global__ __launch_bounds__(256) void blockreduce_kernel(const int* __restrict__ cnt,
                                                          int* __restrict__ bsum, int n) {
  int i = blockIdx.x * 256 + threadIdx.x;
  int v = (i < n) ? cnt[i] : 0;
#pragma unroll
  for (int d = 1; d < 64; d <<= 1) v += __shfl_xor(v, d, 64);
  __shared__ int sh[4];
  if ((threadIdx.x & 63) == 0) sh[threadIdx.x >> 6] = v;
  __syncthreads();
  if (threadIdx.x == 0) bsum[blockIdx.x] = sh[0] + sh[1] + sh[2] + sh[3];
}

__global__ __launch_bounds__(256) void scanb_kernel(const int* __restrict__ bsum,
                                                    int* __restrict__ boff, int nb) {
  __shared__ int sh[256];
  int t = threadIdx.x;
  int orig = (t < nb) ? bsum[t] : 0;
  int v = orig;
  sh[t] = v;
  __syncthreads();
  for (int d = 1; d < 256; d <<= 1) {
    int a = (t >= d) ? sh[t - d] : 0;
    __syncthreads();
    v += a;
    sh[t] = v;
    __syncthreads();
  }
  if (t < nb) boff[t] = v - orig;  // exclusive
}

__global__ __launch_bounds__(256) void blockscan_kernel(
    const int* __restrict__ cnt, const int* __restrict__ boff,
    int* __restrict__ off, int* __restrict__ cur, int n, int total) {
  __shared__ int sh[256];
  int b = blockIdx.x, t = threadIdx.x;
  int i = b * 256 + t;
  int orig = (i < n) ? cnt[i] : 0;
  int v = orig;
  sh[t] = v;
  __syncthreads();
  for (int d = 1; d < 256; d <<= 1) {
    int a = (t >= d) ? sh[t - d] : 0;
    __syncthreads();
    v += a;
    sh[t] = v;
    __syncthreads();
  }
  int excl = v - orig + boff[b];
  if (i < n) { off[i] = excl; cur[i] = excl; }
  if (i == n - 1) off[n] = total;
}

__global__ void scatter_kernel(const int* __restrict__ dstI, int* __restrict__ cur,
                               int* __restrict__ eidx, int E) {
  int e = blockIdx.x * blockDim.x + threadIdx.x;
  if (e < E) {
    int p = atomicAdd(&cur[dstI[e]], 1);
    eidx[p] = e;
  }
}

// per-node wave rank-sort by edge index -> deterministic stable order
// (ascending edge index == np.add.at accumulation order).
__global__ __launch_bounds__(256) void sortseg_kernel(
    const int* __restrict__ off, int* __restrict__ eidx,
    const int* __restrict__ srcI, const float* __restrict__ ew,
    int2* __restrict__ cse, int n) {
  int node = blockIdx.x * 4 + (threadIdx.x >> 6);
  int lane = threadIdx.x & 63;
  if (node >= n) return;
  int s = off[node], e = off[node + 1];
  int deg = e - s;
  if (deg <= 0) return;
  if (deg <= 64) {
    int v = (lane < deg) ? eidx[s + lane] : 2147483647;
    int rank = 0;
    for (int m = 0; m < deg; ++m) {   // deg is wave-uniform; lanes >= deg hold INT_MAX
      int u = __shfl(v, m, 64);
      rank += (u < v) ? 1 : 0;  // edge indices unique
    }
    if (lane < deg)
      cse[s + rank] = make_int2(srcI[v], __float_as_int(ew[v]));
  } else if (lane == 0) {
    for (int i = s + 1; i < e; ++i) {
      int key = eidx[i]; int j = i - 1;
      while (j >= s && eidx[j] > key) { eidx[j + 1] = eidx[j]; --j; }
      eidx[j + 1] = key;
    }
    for (int i = s; i < e; ++i) {
      int v = eidx[i];
      cse[i] = make_int2(srcI[v], __float_as_int(ew[v]));
    }
  }
}

// layer-0 x aggregation for all timesteps (graph is time-invariant)
__global__ __launch_bounds__(256) void aggx0_kernel(
    const int* __restrict__ off, const int2* __restrict__ cse,
    const float* __restrict__ x, float* __restrict__ ax, int n) {
  int node = blockIdx.x * 8 + (threadIdx.x >> 5);
  int lane = threadIdx.x & 31;
  if (node >= n || lane >= 24) return;
  float a = 0.f;
  int s = off[node], e = off[node + 1];
  int i = s;
  for (; i + 3 < e; i += 4) {
    int2 p0 = cse[i], p1 = cse[i + 1], p2 = cse[i + 2], p3 = cse[i + 3];
    float r0 = x[(size_t)p0.x * 24 + lane];
    float r1 = x[(size_t)p1.x * 24 + lane];
    float r2 = x[(size_t)p2.x * 24 + lane];
    float r3 = x[(size_t)p3.x * 24 + lane];
    a = __fadd_rn(a, __fmul_rn(__int_as_float(p0.y), r0));
    a = __fadd_rn(a, __fmul_rn(__int_as_float(p1.y), r1));
    a = __fadd_rn(a, __fmul_rn(__int_as_float(p2.y), r2));
    a = __fadd_rn(a, __fmul_rn(__int_as_float(p3.y), r3));
  }
  for (; i < e; ++i) {
    int2 p = cse[i];
    a = __fadd_rn(a, __fmul_rn(__int_as_float(p.y), x[(size_t)p.x * 24 + lane]));
  }
  ax[(size_t)node * 24 + lane] = a;
}

// ---------------- aggregation (pull, CSR) ----------------
// 16-lane group per node, float4 per lane => one full 256B row per edge.
// cse double-buffer; strict ascending edge order -> bit-identical chains.

__global__ __launch_bounds__(256) void agg1_kernel(
    const int* __restrict__ off, const int2* __restrict__ cse,
    const float* __restrict__ f0, float* __restrict__ o0, int n) {
  const int node = blockIdx.x * 16 + (threadIdx.x >> 4);
  const int g4   = (threadIdx.x & 15) * 4;
  if (node >= n) return;
  int s = off[node], e = off[node + 1];
  float4 acc = make_float4(0.f, 0.f, 0.f, 0.f);
  int i = s;
  if (i + 3 < e) {
    int2 q0 = cse[i], q1 = cse[i + 1], q2 = cse[i + 2], q3 = cse[i + 3];
    for (; i + 7 < e; i += 4) {
      float4 r0 = ld4(f0 + (size_t)q0.x * 64 + g4);
      float4 r1 = ld4(f0 + (size_t)q1.x * 64 + g4);
      float4 r2 = ld4(f0 + (size_t)q2.x * 64 + g4);
      float4 r3 = ld4(f0 + (size_t)q3.x * 64 + g4);
      int2 m0 = cse[i + 4], m1 = cse[i + 5], m2 = cse[i + 6], m3 = cse[i + 7];
      acc = wfma4(acc, __int_as_float(q0.y), r0);
      acc = wfma4(acc, __int_as_float(q1.y), r1);
      acc = wfma4(acc, __int_as_float(q2.y), r2);
      acc = wfma4(acc, __int_as_float(q3.y), r3);
      q0 = m0; q1 = m1; q2 = m2; q3 = m3;
    }
    float4 r0 = ld4(f0 + (size_t)q0.x * 64 + g4);
    float4 r1 = ld4(f0 + (size_t)q1.x * 64 + g4);
    float4 r2 = ld4(f0 + (size_t)q2.x * 64 + g4);
    float4 r3 = ld4(f0 + (size_t)q3.x * 64 + g4);
    acc = wfma4(acc, __int_as_float(q0.y), r0);
    acc = wfma4(acc, __int_as_float(q1.y), r1);
    acc = wfma4(acc, __int_as_float(q2.y), r2);
    acc = wfma4(acc, __int_as_float(q3.y), r3);
    i += 4;
  }
  for (; i < e; ++i) {
    int2 p = cse[i];
    acc = wfma4(acc, __int_as_float(p.y), ld4(f0 + (size_t)p.x * 64 + g4));
  }
  *reinterpret_cast<float4*>(o0 + (size_t)node * 64 + g4) = acc;
}

// fused double gather (two tables, shared index stream), 4-edge unroll + cse dbuf
__global__ __launch_bounds__(256) void agg2_kernel(
    const int* __restrict__ off, const int2* __restrict__ cse,
    const float* __restrict__ f0, float* __restrict__ o0,
    const float* __restrict__ f1, float* __restrict__ o1, int n) {
  const int node = blockIdx.x * 16 + (threadIdx.x >> 4);
  const int g4   = (threadIdx.x & 15) * 4;
  if (node >= n) return;
  int s = off[node], e = off[node + 1];
  float4 a0 = make_float4(0.f, 0.f, 0.f, 0.f);
  float4 a1 = a0;
  int i = s;
  if (i + 3 < e) {
    int2 q0 = cse[i], q1 = cse[i + 1], q2 = cse[i + 2], q3 = cse[i + 3];
    for (; i + 7 < e; i += 4) {
      size_t o0_ = (size_t)q0.x * 64 + g4, o1_ = (size_t)q1.x * 64 + g4;
      size_t o2_ = (size_t)q2.x * 64 + g4, o3_ = (size_t)q3.x * 64 + g4;
      float4 x0 = ld4(f0 + o0_), h0 = ld4(f1 + o0_);
      float4 x1 = ld4(f0 + o1_), h1 = ld4(f1 + o1_);
      float4 x2 = ld4(f0 + o2_), h2 = ld4(f1 + o2_);
      float4 x3 = ld4(f0 + o3_), h3 = ld4(f1 + o3_);
      int2 m0 = cse[i + 4], m1 = cse[i + 5], m2 = cse[i + 6], m3 = cse[i + 7];
      float w0 = __int_as_float(q0.y), w1 = __int_as_float(q1.y);
      float w2 = __int_as_float(q2.y), w3 = __int_as_float(q3.y);
      a0 = wfma4(a0, w0, x0); a1 = wfma4(a1, w0, h0);
      a0 = wfma4(a0, w1, x1); a1 = wfma4(a1, w1, h1);
      a0 = wfma4(a0, w2, x2); a1 = wfma4(a1, w2, h2);
      a0 = wfma4(a0, w3, x3); a1 = wfma4(a1, w3, h3);
      q0 = m0; q1 = m1; q2 = m2; q3 = m3;
    }
    size_t o0_ = (size_t)q0.x * 64 + g4, o1_ = (size_t)q1.x * 64 + g4;
    size_t o2_ = (size_t)q2.x * 64 + g4, o3_ = (size_t)q3.x * 64 + g4;
    float4 x0 = ld4(f0 + o0_), h0 = ld4(f1 + o0_);
    float4 x1 = ld4(f0 + o1_), h1 = ld4(f1 + o1_);
    float4 x2 = ld4(f0 + o2_), h2 = ld4(f1 + o2_);
    float4 x3 = ld4(f0 + o3_), h3 = ld4(f1 + o3_);
    float w0 = __int_as_float(q0.y), w1 = __int_as_float(q1.y);
    float w2 = __int_as_float(q2.y), w3 = __int_as_float(q3.y);
    a0 = wfma4(a0, w0, x0); a1 = wfma4(a1, w0, h0);
    a0 = wfma4(a0, w1, x1); a1 = wfma4(a1, w1, h1);
    a0 = wfma4(a0, w2, x2); a1 = wfma4(a1, w2, h2);
    a0 = wfma4(a0, w3, x3); a1 = wfma4(a1, w3, h3);
    i += 4;
  }
  for (; i < e; ++i) {
    int2 p = cse[i];
    float w = __int_as_float(p.y);
    size_t ro = (size_t)p.x * 64 + g4;
    a0 = wfma4(a0, w, ld4(f0 + ro));
    a1 = wfma4(a1, w, ld4(f1 + ro));
  }
  *reinterpret_cast<float4*>(o0 + (size_t)node * 64 + g4) = a0;
  *reinterpret_cast<float4*>(o1 + (size_t)node * 64 + g4) = a1;
}

// ---------------- gates: zr = sigmoid([aggx, aggh] @ Wg + bg) ----------------
// LDS-staged weights; 8 rows/thread; outputs split into two quads per thread:
// j = (t&15)*4 + i (z half) and j = 64 + (t&15)*4 + i (r half) -> 16B lane
// stride on LDS weight reads (2-way bank alias = free vs 4-way at 32B).
// Per-output K-order chain identical to previous rounds (h part, then x part).

template <int KX>
__global__ __launch_bounds__(256) void gates_kernel(
    const float* __restrict__ aggx, int sx,
    const float* __restrict__ aggh,
    const float* __restrict__ Wg, const float* __restrict__ bg,
    const float* __restrict__ hb, float* __restrict__ zb, float* __restrict__ rhb, int n) {
  __shared__ float wS[(KX + 64) * 128];
  const int t = threadIdx.x;
  {
    float4* d = (float4*)wS;
    const float4* src = (const float4*)Wg;
    const int tot = (KX + 64) * 32;
    for (int idx = t; idx < tot; idx += 256) d[idx] = src[idx];
  }
  __syncthreads();

  const int jz = (t & 15) * 4;        // z-quad column
  const int jr = 64 + jz;             // r-quad column
  const int rb = blockIdx.x * 128 + (t >> 4) * 8;
  if (rb >= n) return;
  const int nr = min(8, n - rb);
  int ro[8];
#pragma unroll
  for (int r = 0; r < 8; ++r) ro[r] = (rb + (r < nr ? r : 0)) * 64;

  float az[8][4], ar[8][4];
#pragma unroll
  for (int r = 0; r < 8; ++r)
#pragma unroll
    for (int i = 0; i < 4; ++i) { az[r][i] = 0.f; ar[r][i] = 0.f; }

  // h part first (K = 64)
  {
    const float* Wh = wS + KX * 128;
    for (int k = 0; k < 64; k += 4) {
      float4 f[8];
#pragma unroll
      for (int r = 0; r < 8; ++r) f[r] = ld4(aggh + ro[r] + k);
#pragma unroll
      for (int kk = 0; kk < 4; ++kk) {
        const float* wr = Wh + (k + kk) * 128;
        float4 wz = ld4(wr + jz), wrq = ld4(wr + jr);
#pragma unroll
        for (int r = 0; r < 8; ++r) {
          float fv = ((const float*)&f[r])[kk];
          fma4(az[r], fv, wz);
          fma4(ar[r], fv, wrq);
        }
      }
    }
  }
  // x part
  if constexpr (KX == 2) {
    float xv[8][2];
#pragma unroll
    for (int r = 0; r < 8; ++r) {
      size_t xo = (size_t)(rb + (r < nr ? r : 0)) * sx;
      xv[r][0] = aggx[xo]; xv[r][1] = aggx[xo + 1];
    }
#pragma unroll
    for (int k = 0; k < 2; ++k) {
      const float* wr = wS + k * 128;
      float4 wz = ld4(wr + jz), wrq = ld4(wr + jr);
#pragma unroll
      for (int r = 0; r < 8; ++r) {
        fma4(az[r], xv[r][k], wz);
        fma4(ar[r], xv[r][k], wrq);
      }
    }
  } else {
    for (int k = 0; k < KX; k += 4) {
      float4 f[8];
#pragma unroll
      for (int r = 0; r < 8; ++r) f[r] = ld4(aggx + ro[r] + k);
#pragma unroll
      for (int kk = 0; kk < 4; ++kk) {
        const float* wr = wS + (k + kk) * 128;
        float4 wz = ld4(wr + jz), wrq = ld4(wr + jr);
#pragma unroll
        for (int r = 0; r < 8; ++r) {
          float fv = ((const float*)&f[r])[kk];
          fma4(az[r], fv, wz);
          fma4(ar[r], fv, wrq);
        }
      }
    }
  }
  // epilogue: z-quad -> zb; r-quad -> rhb (r * h)
#pragma unroll
  for (int i = 0; i < 4; ++i) {
    float bz = bg[jz + i];
    float br = bg[jr + i];
#pragma unroll
    for (int r = 0; r < 8; ++r) {
      if (r < nr) {
        int row = rb + r;
        zb[(size_t)row * 64 + jz + i] = sigmoidf_(az[r][i] + bz);
        float sr = sigmoidf_(ar[r][i] + br);
        rhb[(size_t)row * 64 + jz + i] = __fmul_rn(sr, hb[(size_t)row * 64 + jz + i]);
      }
    }
  }
}

// ---------------- candidate + GRU update ----------------
// LDS-staged weights, 8 rows/thread x 4 outs, 128 rows/block.

template <int KX>
__global__ __launch_bounds__(256) void cand_kernel(
    const float* __restrict__ aggx, int sx,
    const float* __restrict__ aggrh,
    const float* __restrict__ Wc, const float* __restrict__ bc,
    const float* __restrict__ zb, float* __restrict__ hb,
    float* __restrict__ outp, int ostride, int n) {
  __shared__ float wS[(KX + 64) * 64];
  const int t = threadIdx.x;
  {
    float4* d = (float4*)wS;
    const float4* src = (const float4*)Wc;
    const int tot = (KX + 64) * 16;
    for (int idx = t; idx < tot; idx += 256) d[idx] = src[idx];
  }
  __syncthreads();

  const int j0 = (t & 15) * 4;
  const int rb = blockIdx.x * 128 + (t >> 4) * 8;
  if (rb >= n) return;
  const int nr = min(8, n - rb);
  int ro[8];
#pragma unroll
  for (int r = 0; r < 8; ++r) ro[r] = (rb + (r < nr ? r : 0)) * 64;

  float a[8][4];
#pragma unroll
  for (int r = 0; r < 8; ++r)
#pragma unroll
    for (int i = 0; i < 4; ++i) a[r][i] = 0.f;

  {
    const float* Wh = wS + KX * 64;
    for (int k = 0; k < 64; k += 4) {
      float4 f[8];
#pragma unroll
      for (int r = 0; r < 8; ++r) f[r] = ld4(aggrh + ro[r] + k);
#pragma unroll
      for (int kk = 0; kk < 4; ++kk) {
        float4 wa = ld4(Wh + (k + kk) * 64 + j0);
#pragma unroll
        for (int r = 0; r < 8; ++r) fma4(a[r], ((const float*)&f[r])[kk], wa);
      }
    }
  }
  if constexpr (KX == 2) {
    float xv[8][2];
#pragma unroll
    for (int r = 0; r < 8; ++r) {
      size_t xo = (size_t)(rb + (r < nr ? r : 0)) * sx;
      xv[r][0] = aggx[xo]; xv[r][1] = aggx[xo + 1];
    }
#pragma unroll
    for (int k = 0; k < 2; ++k) {
      float4 wa = ld4(wS + k * 64 + j0);
#pragma unroll
      for (int r = 0; r < 8; ++r) fma4(a[r], xv[r][k], wa);
    }
  } else {
    for (int k = 0; k < KX; k += 4) {
      float4 f[8];
#pragma unroll
      for (int r = 0; r < 8; ++r) f[r] = ld4(aggx + ro[r] + k);
#pragma unroll
      for (int kk = 0; kk < 4; ++kk) {
        float4 wa = ld4(wS + (k + kk) * 64 + j0);
#pragma unroll
        for (int r = 0; r < 8; ++r) fma4(a[r], ((const float*)&f[r])[kk], wa);
      }
    }
  }
#pragma unroll
  for (int i = 0; i < 4; ++i) {
    int j = j0 + i;
    float b = bc[j];
#pragma unroll
    for (int r = 0; r < 8; ++r) {
      if (r < nr) {
        int row = rb + r;
        float c = tanhf(a[r][i] + b);
        float z = zb[(size_t)row * 64 + j];
        float h = hb[(size_t)row * 64 + j];
        float hn = __fadd_rn(__fmul_rn(z, h), __fmul_rn(1.f - z, c));  // np rounding
        hb[(size_t)row * 64 + j] = hn;
        outp[(size_t)row * ostride + j] = hn;
      }
    }
  }
}

// ---------------- launch ----------------

extern "C" void kernel_launch(void* const* d_in, const int* in_sizes, int n_in,
                              void* d_out, int out_size, void* d_ws, size_t ws_size,
                              hipStream_t stream) {
  const float* x   = (const float*)d_in[0];
  const float* h0  = (const float*)d_in[1];
  const int*   ei  = (const int*)  d_in[2];
  const float* ew  = (const float*)d_in[3];
  const float* Wg0 = (const float*)d_in[4];
  const float* bg0 = (const float*)d_in[5];
  const float* Wc0 = (const float*)d_in[6];
  const float* bc0 = (const float*)d_in[7];
  const float* Wg1 = (const float*)d_in[8];
  const float* bg1 = (const float*)d_in[9];
  const float* Wc1 = (const float*)d_in[10];
  const float* bc1 = (const float*)d_in[11];

  const int N = in_sizes[0] / 24;  // T*F = 24
  const int E = in_sizes[2] / 2;
  const int NH = N * 64;
  const int NB = (N + 255) / 256;

  float* h1   = (float*)d_out;      // N*64
  float* h2   = h1 + NH;            // N*64
  float* out2 = h2 + NH;            // N*T*64, layout [n][t][j]

  char* w = (char*)d_ws;
  auto alloc = [&](size_t bytes) {
    char* p = w;
    w += (bytes + 255) & ~(size_t)255;
    return p;
  };
  int*   cnt   = (int*)  alloc((size_t)N * 4);
  int*   off   = (int*)  alloc((size_t)(N + 1) * 4);
  int*   cur   = (int*)  alloc((size_t)N * 4);
  int2*  cse   = (int2*) alloc((size_t)E * 8);   // packed (src, weight)
  int*   bsum  = (int*)  alloc(256 * 4);
  int*   boff  = (int*)  alloc(256 * 4);
  float* aggx0 = (float*)alloc((size_t)N * 24 * 4);
  float* aggx1 = (float*)alloc((size_t)NH * 4);
  float* aggh  = (float*)alloc((size_t)NH * 4);
  float* aggrh = (float*)alloc((size_t)NH * 4);
  float* zb    = (float*)alloc((size_t)NH * 4);
  float* rhb   = (float*)alloc((size_t)NH * 4);
  float* o1t   = (float*)alloc((size_t)NH * 4);
  int*   eidx  = (int*)aggx1;  // alias: aggx1 first written inside the t-loop

  const int* srcI = ei;
  const int* dstI = ei + E;

  hipMemcpyAsync(d_out, h0, (size_t)2 * NH * 4, hipMemcpyDeviceToDevice, stream);

  // deterministic & stable CSR: sorted by (dst, original edge index)
  hipMemsetAsync(cnt, 0, (size_t)N * 4, stream);
  count_kernel<<<(E + 255) / 256, 256, 0, stream>>>(dstI, cnt, E);
  blockreduce_kernel<<<NB, 256, 0, stream>>>(cnt, bsum, N);
  scanb_kernel<<<1, 256, 0, stream>>>(bsum, boff, NB);
  blockscan_kernel<<<NB, 256, 0, stream>>>(cnt, boff, off, cur, N, E);
  scatter_kernel<<<(E + 255) / 256, 256, 0, stream>>>(dstI, cur, eidx, E);
  sortseg_kernel<<<(N + 3) / 4, 256, 0, stream>>>(off, eidx, srcI, ew, cse, N);

  // layer-0 x aggregation, all timesteps at once (graph is time-invariant)
  aggx0_kernel<<<(N + 7) / 8, 256, 0, stream>>>(off, cse, x, aggx0, N);

  const int gagg = (N + 15) / 16;   // 16 nodes/block (16-lane group per node)
  const int gmm  = (N + 127) / 128; // matmuls: 128 rows/block, 8 rows/thread

  for (int t = 0; t < 12; ++t) {
    // ---- layer 0 ----
    agg1_kernel<<<gagg, 256, 0, stream>>>(off, cse, h1, aggh, N);
    gates_kernel<2><<<gmm, 256, 0, stream>>>(aggx0 + 2 * t, 24, aggh, Wg0, bg0, h1, zb, rhb, N);
    agg1_kernel<<<gagg, 256, 0, stream>>>(off, cse, rhb, aggrh, N);
    cand_kernel<2><<<gmm, 256, 0, stream>>>(aggx0 + 2 * t, 24, aggrh, Wc0, bc0, zb, h1, o1t, 64, N);
    // ---- layer 1 ----
    agg2_kernel<<<gagg, 256, 0, stream>>>(off, cse, o1t, aggx1, h2, aggh, N);
    gates_kernel<64><<<gmm, 256, 0, stream>>>(aggx1, 64, aggh, Wg1, bg1, h2, zb, rhb, N);
    agg1_kernel<<<gagg, 256, 0, stream>>>(off, cse, rhb, aggrh, N);
    cand_kernel<64><<<gmm, 256, 0, stream>>>(aggx1, 64, aggrh, Wc1, bc1, zb, h2,
                                             out2 + (size_t)t * 64, 12 * 64, N);
  }
}